// Round 5
// baseline (149.977 us; speedup 1.0000x reference)
//
#include <hip/hip_runtime.h>
#include <hip/hip_bf16.h>

// FourierKANLayer: y[n,o] = sum_{i,g} cos(x[n,i]*(g+1))*C[0,o,i,g]
//                         + sin(x[n,i]*(g+1))*C[1,o,i,g] + bias[o]
// N=8192 rows, I=512, O=512, G=8  ->  GEMM  [N x K] * [K x O], K = I*16 = 8192
// Feature order: k = i*16 + 2*g + t   (t=0 cos, t=1 sin)
// Round 5: A (trig) stays in double-buffered swizzled LDS (shared-trig, cheap
// VALU). B fragments are REGISTER-prefetched one full kt ahead from the
// L2-resident per-XCD panel (no LDS for B at all): LDS traffic 88->40 KB per
// block-kt, no vmcnt-drain cost at the barrier, ~1300 cyc latency cover.

typedef __attribute__((ext_vector_type(8))) short s16x8;
typedef __attribute__((ext_vector_type(4))) int   i32x4;
typedef __attribute__((ext_vector_type(4))) float f32x4;

#define NROWS 8192
#define IDIM  512
#define ODIM  512
#define KDIM  8192   // IDIM*16

static __device__ __forceinline__ short f2bf(float f) {
    union { float f; unsigned u; } v; v.f = f;
    unsigned r = v.u + 0x7fffu + ((v.u >> 16) & 1u);  // RNE
    return (short)(r >> 16);
}

static __device__ __forceinline__ int pkbf(float c, float s) {
    union { __hip_bfloat162 h; int i; } u;
    u.h = __float22bfloat162_rn(make_float2(c, s));   // low = cos, high = sin
    return u.i;
}

// ---- prep: coeffs [2][O][I][G] f32  ->  Wb[O][K] bf16, k = i*16 + 2g + t ----
__global__ __launch_bounds__(256) void fkan_prep(const float* __restrict__ cf,
                                                 short* __restrict__ Wb) {
    const int o = blockIdx.x;
    const int tid = threadIdx.x;
#pragma unroll
    for (int rep = 0; rep < 2; ++rep) {
        const int i = tid + rep * 256;
        const float* c0 = cf + (o * 512 + i) * 8;            // t=0
        const float* c1 = cf + ((512 + o) * 512 + i) * 8;    // t=1
        float4 a0 = *(const float4*)c0;
        float4 a1 = *(const float4*)(c0 + 4);
        float4 b0 = *(const float4*)c1;
        float4 b1 = *(const float4*)(c1 + 4);
        s16x8 lo, hi;
        lo[0] = f2bf(a0.x); lo[1] = f2bf(b0.x);
        lo[2] = f2bf(a0.y); lo[3] = f2bf(b0.y);
        lo[4] = f2bf(a0.z); lo[5] = f2bf(b0.z);
        lo[6] = f2bf(a0.w); lo[7] = f2bf(b0.w);
        hi[0] = f2bf(a1.x); hi[1] = f2bf(b1.x);
        hi[2] = f2bf(a1.y); hi[3] = f2bf(b1.y);
        hi[4] = f2bf(a1.z); hi[5] = f2bf(b1.z);
        hi[6] = f2bf(a1.w); hi[7] = f2bf(b1.w);
        *(s16x8*)(Wb + o * KDIM + i * 16)     = lo;
        *(s16x8*)(Wb + o * KDIM + i * 16 + 8) = hi;
    }
}

// ---- fused GEMM: BM=128, BN=128, BK=64, 256 threads (4 waves, 2x2) ----
// A (trig features) in double-buffered swizzled LDS; B frags register-
// prefetched one kt ahead from global (L2-resident per-XCD panel).
// KSPLIT=2: grid 512, each block does half of K, writes f32 partial (no bias).
// KSPLIT=1: grid 256, full K, writes out + bias (fallback when ws too small).
template <int KSPLIT>
__global__ __launch_bounds__(256, 2) void fkan_gemm(const float* __restrict__ x,
                                                    const short* __restrict__ Wb,
                                                    const float* __restrict__ bias,
                                                    float* __restrict__ outp) {
    __shared__ short As[2][128 * 64];   // [buf][row n_local][64 k] swizzled chunks

    const int bid = blockIdx.x;
    int bn, kc, bm;
    if (KSPLIT == 2) {
        // 8 (bn,kc) combos -> 8 XCDs; each XCD's 1MB B-chunk is L2-resident.
        const int xcd = bid & 7;
        bn = xcd & 3; kc = xcd >> 2; bm = bid >> 3;          // bm in [0,64)
    } else {
        const int xcd = bid & 7, idx = bid >> 3;
        bn = xcd & 3; kc = 0; bm = idx + (xcd >> 2) * 32;    // bm in [0,64)
    }
    const int n0 = bm * 128, o0 = bn * 128;
    const int NKT = 128 / KSPLIT;          // kt iterations (even)
    const int i0 = kc * (512 / KSPLIT);    // starting input-dim index
    const int kbase = i0 * 16;             // starting k index in Wb

    const int tid = threadIdx.x;
    const int wid = tid >> 6, lane = tid & 63;
    const int lrow = lane & 15, lk = lane >> 4;
    const int wr = wid >> 1, wc = wid & 1;

    f32x4 acc[4][4];
#pragma unroll
    for (int a = 0; a < 4; ++a)
#pragma unroll
        for (int b = 0; b < 4; ++b) {
            f32x4 z = {0.f, 0.f, 0.f, 0.f};
            acc[a][b] = z;
        }

    // per-lane B row pointers: col = o0 + wc*64 + nf*16 + lrow, chunk lk
    const short* bRow[4];
#pragma unroll
    for (int nf = 0; nf < 4; ++nf)
        bRow[nf] = Wb + (size_t)(o0 + wc * 64 + nf * 16 + lrow) * KDIM + kbase + lk * 8;

    // A staging assignment: thread -> row nl, two x values (i = i0 + kt*4 + isel*2 + ii)
    const int nl = tid >> 1, isel = tid & 1;
    const float* xrow = x + (n0 + nl) * 512 + i0 + isel * 2;

    // stage tile's A into buffer base (trig only)
    auto stageA = [&](short* Ab, float2 xvv) {
#pragma unroll
        for (int ii = 0; ii < 2; ++ii) {
            const float xx = ii ? xvv.y : xvv.x;
            float s1, c1;
            __sincosf(xx, &s1, &c1);
            float c = c1, s = s1;
            i32x4 lo, hi;
#pragma unroll
            for (int g = 0; g < 8; ++g) {
                const int p = pkbf(c, s);
                if (g < 4) lo[g] = p; else hi[g - 4] = p;
                const float t1 = s * s1, t2 = c * s1;
                const float cn = __builtin_fmaf(c, c1, -t1);  // cos(k+1)
                s = __builtin_fmaf(s, c1, t2);                // sin(k+1)
                c = cn;
            }
            const int il = isel * 2 + ii;
            const int cb0 = il * 2;  // logical 16B-chunk index (0..7)
            *(i32x4*)&Ab[nl * 64 + ((cb0 ^ (nl & 7))) * 8]       = lo;
            *(i32x4*)&Ab[nl * 64 + (((cb0 + 1) ^ (nl & 7))) * 8] = hi;
        }
    };

    auto loadB = [&](int t, s16x8 b[2][4]) {
#pragma unroll
        for (int ksub = 0; ksub < 2; ++ksub)
#pragma unroll
            for (int nf = 0; nf < 4; ++nf)
                b[ksub][nf] = *(const s16x8*)(bRow[nf] + t * 64 + ksub * 32);
    };

    auto readA = [&](const short* Ab, s16x8 af[2][4]) {
#pragma unroll
        for (int ksub = 0; ksub < 2; ++ksub)
#pragma unroll
            for (int mf = 0; mf < 4; ++mf) {
                const int row = wr * 64 + mf * 16 + lrow;
                af[ksub][mf] = *(const s16x8*)&Ab[row * 64 + ((ksub * 4 + lk) ^ (row & 7)) * 8];
            }
    };

    auto mfma16 = [&](s16x8 af[2][4], s16x8 b[2][4]) {
#pragma unroll
        for (int ksub = 0; ksub < 2; ++ksub)
#pragma unroll
            for (int mf = 0; mf < 4; ++mf)
#pragma unroll
                for (int nf = 0; nf < 4; ++nf)
                    acc[mf][nf] = __builtin_amdgcn_mfma_f32_16x16x32_bf16(
                        af[ksub][mf], b[ksub][nf], acc[mf][nf], 0, 0, 0);
    };

    s16x8 b0[2][4], b1[2][4];
    s16x8 af[2][4];

    float2 xv = *(const float2*)xrow;          // x for tile 0
    stageA(As[0], xv);
    loadB(0, b0);
    xv = *(const float2*)(xrow + 4);           // x for tile 1
    __syncthreads();

    for (int kt = 0; kt < NKT; kt += 2) {
        // ---- even half: consume As[0], b0; prepare tile kt+1
        loadB(kt + 1, b1);                     // B prefetch, ~full kt of cover
        readA(As[0], af);
        stageA(As[1], xv);                     // A(kt+1)
        if (kt + 2 < NKT) xv = *(const float2*)(xrow + (kt + 2) * 4);
        mfma16(af, b0);
        __syncthreads();

        // ---- odd half: consume As[1], b1; prepare tile kt+2
        if (kt + 2 < NKT) loadB(kt + 2, b0);
        readA(As[1], af);
        if (kt + 2 < NKT) {
            stageA(As[0], xv);                 // A(kt+2)
            if (kt + 3 < NKT) xv = *(const float2*)(xrow + (kt + 3) * 4);
        }
        mfma16(af, b1);
        __syncthreads();
    }

    // ---- epilogue: D layout col = lane&15 (o), row = (lane>>4)*4 + reg (n)
    float* dst = (KSPLIT == 2) ? (outp + (size_t)kc * (NROWS * ODIM)) : outp;
#pragma unroll
    for (int nf = 0; nf < 4; ++nf) {
        const int oc = o0 + wc * 64 + nf * 16 + lrow;
        const float bv = (KSPLIT == 1) ? bias[oc] : 0.f;
#pragma unroll
        for (int mf = 0; mf < 4; ++mf) {
            const f32x4 v = acc[mf][nf];
            const int rbase = n0 + wr * 64 + mf * 16 + lk * 4;
#pragma unroll
            for (int j = 0; j < 4; ++j)
                dst[(rbase + j) * 512 + oc] = v[j] + bv;
        }
    }
}

// ---- combine: out = P0 + P1 + bias ----
__global__ __launch_bounds__(256) void fkan_combine(const float* __restrict__ P,
                                                    const float* __restrict__ bias,
                                                    float* __restrict__ out) {
    const int total = NROWS * ODIM / 4;  // float4 count
    for (int idx = blockIdx.x * 256 + threadIdx.x; idx < total;
         idx += gridDim.x * 256) {
        float4 a = ((const float4*)P)[idx];
        float4 b = ((const float4*)P)[total + idx];
        float4 c = ((const float4*)bias)[idx & 127];
        float4 r;
        r.x = a.x + b.x + c.x;
        r.y = a.y + b.y + c.y;
        r.z = a.z + b.z + c.z;
        r.w = a.w + b.w + c.w;
        ((float4*)out)[idx] = r;
    }
}

extern "C" void kernel_launch(void* const* d_in, const int* in_sizes, int n_in,
                              void* d_out, int out_size, void* d_ws, size_t ws_size,
                              hipStream_t stream) {
    const float* x    = (const float*)d_in[0];
    const float* cf   = (const float*)d_in[1];
    const float* bias = (const float*)d_in[2];
    float* out = (float*)d_out;

    const size_t partial_bytes = (size_t)2 * NROWS * ODIM * 4;   // 33.6 MB
    const size_t wb_bytes = (size_t)ODIM * KDIM * 2;             // 8.4 MB

    if (ws_size >= partial_bytes + wb_bytes) {
        float* P  = (float*)d_ws;
        short* Wb = (short*)((char*)d_ws + partial_bytes);
        fkan_prep<<<512, 256, 0, stream>>>(cf, Wb);
        fkan_gemm<2><<<512, 256, 0, stream>>>(x, Wb, bias, P);
        fkan_combine<<<1024, 256, 0, stream>>>(P, bias, out);
    } else {
        short* Wb = (short*)d_ws;
        fkan_prep<<<512, 256, 0, stream>>>(cf, Wb);
        fkan_gemm<1><<<256, 256, 0, stream>>>(x, Wb, bias, out);
    }
}

// Round 6
// 102.311 us; speedup vs baseline: 1.4659x; 1.4659x over previous
//
#include <hip/hip_runtime.h>
#include <hip/hip_bf16.h>

// FourierKANLayer: y[n,o] = sum_{i,g} cos(x[n,i]*(g+1))*C[0,o,i,g]
//                         + sin(x[n,i]*(g+1))*C[1,o,i,g] + bias[o]
// N=8192 rows, I=512, O=512, G=8  ->  GEMM  [N x K] * [K x O], K = I*16 = 8192
// Feature order: k = i*16 + 2*g + t   (t=0 cos, t=1 sin)
// Round 6: revert to the R3 structure (A trig in dbuf swizzled LDS, B via
// global_load_lds dbuf, one barrier per kt) -- R4/R5's direct-global B both
// regressed (VMEM-to-VGPR stall, no TLP). Add: (1) s_setprio around MFMA
// cluster (2 blocks/CU = phase-split waves to arbitrate), (2) bf16 partials.

typedef __attribute__((ext_vector_type(8))) short s16x8;
typedef __attribute__((ext_vector_type(4))) int   i32x4;
typedef __attribute__((ext_vector_type(4))) float f32x4;

#define NROWS 8192
#define IDIM  512
#define ODIM  512
#define KDIM  8192   // IDIM*16

static __device__ __forceinline__ short f2bf(float f) {
    union { float f; unsigned u; } v; v.f = f;
    unsigned r = v.u + 0x7fffu + ((v.u >> 16) & 1u);  // RNE
    return (short)(r >> 16);
}

static __device__ __forceinline__ float bf2f(short h) {
    union { unsigned u; float f; } v;
    v.u = ((unsigned)(unsigned short)h) << 16;
    return v.f;
}

static __device__ __forceinline__ int pkbf(float c, float s) {
    union { __hip_bfloat162 h; int i; } u;
    u.h = __float22bfloat162_rn(make_float2(c, s));   // low = cos, high = sin
    return u.i;
}

// ---- prep: coeffs [2][O][I][G] f32  ->  Wb[O][K] bf16, k = i*16 + 2g + t ----
__global__ __launch_bounds__(256) void fkan_prep(const float* __restrict__ cf,
                                                 short* __restrict__ Wb) {
    const int o = blockIdx.x;
    const int tid = threadIdx.x;
#pragma unroll
    for (int rep = 0; rep < 2; ++rep) {
        const int i = tid + rep * 256;
        const float* c0 = cf + (o * 512 + i) * 8;            // t=0
        const float* c1 = cf + ((512 + o) * 512 + i) * 8;    // t=1
        float4 a0 = *(const float4*)c0;
        float4 a1 = *(const float4*)(c0 + 4);
        float4 b0 = *(const float4*)c1;
        float4 b1 = *(const float4*)(c1 + 4);
        s16x8 lo, hi;
        lo[0] = f2bf(a0.x); lo[1] = f2bf(b0.x);
        lo[2] = f2bf(a0.y); lo[3] = f2bf(b0.y);
        lo[4] = f2bf(a0.z); lo[5] = f2bf(b0.z);
        lo[6] = f2bf(a0.w); lo[7] = f2bf(b0.w);
        hi[0] = f2bf(a1.x); hi[1] = f2bf(b1.x);
        hi[2] = f2bf(a1.y); hi[3] = f2bf(b1.y);
        hi[4] = f2bf(a1.z); hi[5] = f2bf(b1.z);
        hi[6] = f2bf(a1.w); hi[7] = f2bf(b1.w);
        *(s16x8*)(Wb + o * KDIM + i * 16)     = lo;
        *(s16x8*)(Wb + o * KDIM + i * 16 + 8) = hi;
    }
}

// ---- fused GEMM: BM=128, BN=128, BK=64, 256 threads (4 waves, 2x2) ----
// KSPLIT=2: grid 512, each block does half of K, writes bf16 partial (no bias).
// KSPLIT=1: grid 256, full K, writes f32 out + bias (fallback, small ws).
template <int KSPLIT>
__global__ __launch_bounds__(256, 2) void fkan_gemm(const float* __restrict__ x,
                                                    const short* __restrict__ Wb,
                                                    const float* __restrict__ bias,
                                                    void* __restrict__ outp) {
    __shared__ short As[2][128 * 64];   // [buf][row n_local][64 k] swizzled chunks
    __shared__ short Bs[2][128 * 64];   // [buf][row o_local][64 k] swizzled content

    const int bid = blockIdx.x;
    int bn, kc, bm;
    if (KSPLIT == 2) {
        // 8 (bn,kc) combos -> 8 XCDs; each XCD's 1MB B-chunk is L2-resident.
        const int xcd = bid & 7;
        bn = xcd & 3; kc = xcd >> 2; bm = bid >> 3;          // bm in [0,64)
    } else {
        const int xcd = bid & 7, idx = bid >> 3;
        bn = xcd & 3; kc = 0; bm = idx + (xcd >> 2) * 32;    // bm in [0,64)
    }
    const int n0 = bm * 128, o0 = bn * 128;
    const int NKT = 128 / KSPLIT;          // kt iterations
    const int i0 = kc * (512 / KSPLIT);    // starting input-dim index
    const int kbase = i0 * 16;             // starting k index in Wb

    const int tid = threadIdx.x;
    const int wid = tid >> 6, lane = tid & 63;
    const int lrow = lane & 15, lk = lane >> 4;
    const int wr = wid >> 1, wc = wid & 1;

    f32x4 acc[4][4];
#pragma unroll
    for (int a = 0; a < 4; ++a)
#pragma unroll
        for (int b = 0; b < 4; ++b) {
            f32x4 z = {0.f, 0.f, 0.f, 0.f};
            acc[a][b] = z;
        }

    // A staging assignment: thread -> row nl, two x values (i = i0 + kt*4 + isel*2 + ii)
    const int nl = tid >> 1, isel = tid & 1;
    const float* xrow = x + (n0 + nl) * 512 + i0 + isel * 2;

    // stage tile t into buffer nb (gload_lds B first, then trig A)
    auto stage = [&](int t, int nb, float2 xvv) {
#pragma unroll
        for (int w = 0; w < 4; ++w) {
            const int chunk = w * 256 + tid;      // 16B chunk within tile
            const int r = chunk >> 3, pc = chunk & 7;
            const int lc = pc ^ (r & 7);
            const short* src = Wb + (o0 + r) * KDIM + kbase + t * 64 + lc * 8;
            short* ldst = &Bs[nb][w * 2048 + wid * 512];   // wave-uniform base
            __builtin_amdgcn_global_load_lds(
                (const __attribute__((address_space(1))) void*)src,
                (__attribute__((address_space(3))) void*)ldst, 16, 0, 0);
        }
#pragma unroll
        for (int ii = 0; ii < 2; ++ii) {
            const float xx = ii ? xvv.y : xvv.x;
            float s1, c1;
            __sincosf(xx, &s1, &c1);
            float c = c1, s = s1;
            i32x4 lo, hi;
#pragma unroll
            for (int g = 0; g < 8; ++g) {
                const int p = pkbf(c, s);
                if (g < 4) lo[g] = p; else hi[g - 4] = p;
                const float t1 = s * s1, t2 = c * s1;
                const float cn = __builtin_fmaf(c, c1, -t1);  // cos(k+1)
                s = __builtin_fmaf(s, c1, t2);                // sin(k+1)
                c = cn;
            }
            const int il = isel * 2 + ii;
            const int cb0 = il * 2;  // logical 16B-chunk index (0..7)
            *(i32x4*)&As[nb][nl * 64 + ((cb0 ^ (nl & 7))) * 8]       = lo;
            *(i32x4*)&As[nb][nl * 64 + (((cb0 + 1) ^ (nl & 7))) * 8] = hi;
        }
    };

    float2 xv = *(const float2*)xrow;          // x for tile 0
    stage(0, 0, xv);
    xv = *(const float2*)(xrow + 4);           // x for tile 1
    __syncthreads();

    for (int kt = 0; kt < NKT; ++kt) {
        const int cur = kt & 1;
        const short* Ab = As[cur];
        const short* Bb = Bs[cur];

        // ---- read all fragments for this tile
        s16x8 af[2][4], bfr[2][4];
#pragma unroll
        for (int ksub = 0; ksub < 2; ++ksub) {
#pragma unroll
            for (int mf = 0; mf < 4; ++mf) {
                const int row = wr * 64 + mf * 16 + lrow;
                af[ksub][mf] = *(const s16x8*)&Ab[row * 64 + ((ksub * 4 + lk) ^ (row & 7)) * 8];
            }
#pragma unroll
            for (int nf = 0; nf < 4; ++nf) {
                const int row = wc * 64 + nf * 16 + lrow;
                bfr[ksub][nf] = *(const s16x8*)&Bb[row * 64 + ((ksub * 4 + lk) ^ (row & 7)) * 8];
            }
        }

        // ---- stage next tile into the other buffer (overlaps with MFMA below)
        if (kt + 1 < NKT) {
            stage(kt + 1, cur ^ 1, xv);
            if (kt + 2 < NKT) xv = *(const float2*)(xrow + (kt + 2) * 4);
        }

        // ---- MFMA cluster (T5: bump wave priority so MFMA-phase waves win
        //      arbitration against the other block's staging-phase waves)
        __builtin_amdgcn_s_setprio(1);
#pragma unroll
        for (int ksub = 0; ksub < 2; ++ksub)
#pragma unroll
            for (int mf = 0; mf < 4; ++mf)
#pragma unroll
                for (int nf = 0; nf < 4; ++nf)
                    acc[mf][nf] = __builtin_amdgcn_mfma_f32_16x16x32_bf16(
                        af[ksub][mf], bfr[ksub][nf], acc[mf][nf], 0, 0, 0);
        __builtin_amdgcn_s_setprio(0);

        __syncthreads();   // drains vmcnt+lgkm; protects both buffers
    }

    // ---- epilogue: D layout col = lane&15 (o), row = (lane>>4)*4 + reg (n)
    if (KSPLIT == 2) {
        unsigned short* dst = (unsigned short*)outp + (size_t)kc * (NROWS * ODIM);
#pragma unroll
        for (int nf = 0; nf < 4; ++nf) {
            const int oc = o0 + wc * 64 + nf * 16 + lrow;
#pragma unroll
            for (int mf = 0; mf < 4; ++mf) {
                const f32x4 v = acc[mf][nf];
                const int rbase = n0 + wr * 64 + mf * 16 + lk * 4;
#pragma unroll
                for (int j = 0; j < 4; ++j)
                    dst[(size_t)(rbase + j) * 512 + oc] = (unsigned short)f2bf(v[j]);
            }
        }
    } else {
        float* dst = (float*)outp;
#pragma unroll
        for (int nf = 0; nf < 4; ++nf) {
            const int oc = o0 + wc * 64 + nf * 16 + lrow;
            const float bv = bias[oc];
#pragma unroll
            for (int mf = 0; mf < 4; ++mf) {
                const f32x4 v = acc[mf][nf];
                const int rbase = n0 + wr * 64 + mf * 16 + lk * 4;
#pragma unroll
                for (int j = 0; j < 4; ++j)
                    dst[(size_t)(rbase + j) * 512 + oc] = v[j] + bv;
            }
        }
    }
}

// ---- combine: out = f32(P0) + f32(P1) + bias  (P is bf16) ----
__global__ __launch_bounds__(256) void fkan_combine(const short* __restrict__ P,
                                                    const float* __restrict__ bias,
                                                    float* __restrict__ out) {
    const int total = NROWS * ODIM;            // elements
    const int stride = gridDim.x * 256 * 8;
    for (int e = (blockIdx.x * 256 + threadIdx.x) * 8; e < total; e += stride) {
        s16x8 a = *(const s16x8*)(P + e);
        s16x8 b = *(const s16x8*)(P + total + e);
        const int col = e & 511;
        float4 c0 = *(const float4*)(bias + col);
        float4 c1 = *(const float4*)(bias + col + 4);
        float4 r0, r1;
        r0.x = bf2f(a[0]) + bf2f(b[0]) + c0.x;
        r0.y = bf2f(a[1]) + bf2f(b[1]) + c0.y;
        r0.z = bf2f(a[2]) + bf2f(b[2]) + c0.z;
        r0.w = bf2f(a[3]) + bf2f(b[3]) + c0.w;
        r1.x = bf2f(a[4]) + bf2f(b[4]) + c1.x;
        r1.y = bf2f(a[5]) + bf2f(b[5]) + c1.y;
        r1.z = bf2f(a[6]) + bf2f(b[6]) + c1.z;
        r1.w = bf2f(a[7]) + bf2f(b[7]) + c1.w;
        *(float4*)(out + e)     = r0;
        *(float4*)(out + e + 4) = r1;
    }
}

extern "C" void kernel_launch(void* const* d_in, const int* in_sizes, int n_in,
                              void* d_out, int out_size, void* d_ws, size_t ws_size,
                              hipStream_t stream) {
    const float* x    = (const float*)d_in[0];
    const float* cf   = (const float*)d_in[1];
    const float* bias = (const float*)d_in[2];
    float* out = (float*)d_out;

    const size_t partial_bytes = (size_t)2 * NROWS * ODIM * 2;   // 16.8 MB (bf16)
    const size_t wb_bytes = (size_t)ODIM * KDIM * 2;             // 8.4 MB

    if (ws_size >= partial_bytes + wb_bytes) {
        short* P  = (short*)d_ws;
        short* Wb = (short*)((char*)d_ws + partial_bytes);
        fkan_prep<<<512, 256, 0, stream>>>(cf, Wb);
        fkan_gemm<2><<<512, 256, 0, stream>>>(x, Wb, bias, (void*)P);
        fkan_combine<<<2048, 256, 0, stream>>>(P, bias, out);
    } else {
        short* Wb = (short*)d_ws;
        fkan_prep<<<512, 256, 0, stream>>>(cf, Wb);
        fkan_gemm<1><<<256, 256, 0, stream>>>(x, Wb, bias, (void*)out);
    }
}

// Round 7
// 92.560 us; speedup vs baseline: 1.6203x; 1.1054x over previous
//
#include <hip/hip_runtime.h>
#include <hip/hip_bf16.h>

// FourierKANLayer: y[n,o] = sum_{i,g} cos(x[n,i]*(g+1))*C[0,o,i,g]
//                         + sin(x[n,i]*(g+1))*C[1,o,i,g] + bias[o]
// N=8192, I=512, O=512, G=8  ->  GEMM [N x K]*[K x O], K = I*16 = 8192
// Feature order: k = i*16 + 2*g + t (t=0 cos, t=1 sin)
// Round 7: BN=512 full-O tile kills the 4x trig redundancy (trig was 46%
// VALUBusy and the wall). BM=128,BN=512,BK=32, 8 waves (2x4), KSPLIT=4,
// grid 256 = 1 block/CU. A staged 2kt at a time (dbuf 2x16KB), B via
// global_load_lds (dbuf 2x32KB, 2 o-rows packed per 128B LDS row, XOR swz).

typedef __attribute__((ext_vector_type(8))) short s16x8;
typedef __attribute__((ext_vector_type(4))) int   i32x4;
typedef __attribute__((ext_vector_type(4))) float f32x4;

#define NROWS 8192
#define IDIM  512
#define ODIM  512
#define KDIM  8192   // IDIM*16

static __device__ __forceinline__ short f2bf(float f) {
    union { float f; unsigned u; } v; v.f = f;
    unsigned r = v.u + 0x7fffu + ((v.u >> 16) & 1u);  // RNE
    return (short)(r >> 16);
}

static __device__ __forceinline__ float bf2f(short h) {
    union { unsigned u; float f; } v;
    v.u = ((unsigned)(unsigned short)h) << 16;
    return v.f;
}

static __device__ __forceinline__ int pkbf(float c, float s) {
    union { __hip_bfloat162 h; int i; } u;
    u.h = __float22bfloat162_rn(make_float2(c, s));   // low = cos, high = sin
    return u.i;
}

// ---- prep: coeffs [2][O][I][G] f32  ->  Wb[O][K] bf16, k = i*16 + 2g + t ----
__global__ __launch_bounds__(256) void fkan_prep(const float* __restrict__ cf,
                                                 short* __restrict__ Wb) {
    const int o = blockIdx.x;
    const int tid = threadIdx.x;
#pragma unroll
    for (int rep = 0; rep < 2; ++rep) {
        const int i = tid + rep * 256;
        const float* c0 = cf + (o * 512 + i) * 8;            // t=0
        const float* c1 = cf + ((512 + o) * 512 + i) * 8;    // t=1
        float4 a0 = *(const float4*)c0;
        float4 a1 = *(const float4*)(c0 + 4);
        float4 b0 = *(const float4*)c1;
        float4 b1 = *(const float4*)(c1 + 4);
        s16x8 lo, hi;
        lo[0] = f2bf(a0.x); lo[1] = f2bf(b0.x);
        lo[2] = f2bf(a0.y); lo[3] = f2bf(b0.y);
        lo[4] = f2bf(a0.z); lo[5] = f2bf(b0.z);
        lo[6] = f2bf(a0.w); lo[7] = f2bf(b0.w);
        hi[0] = f2bf(a1.x); hi[1] = f2bf(b1.x);
        hi[2] = f2bf(a1.y); hi[3] = f2bf(b1.y);
        hi[4] = f2bf(a1.z); hi[5] = f2bf(b1.z);
        hi[6] = f2bf(a1.w); hi[7] = f2bf(b1.w);
        *(s16x8*)(Wb + o * KDIM + i * 16)     = lo;
        *(s16x8*)(Wb + o * KDIM + i * 16 + 8) = hi;
    }
}

// ---- main GEMM: BM=128, BN=512, BK=32, 512 threads (8 waves, 2x4) ----
// grid 256 (KSPLIT=4, 1 block/CU). Writes bf16 partial P[kc][N][O].
__global__ __launch_bounds__(512, 2) void fkan_gemm4(const float* __restrict__ x,
                                                     const short* __restrict__ Wb,
                                                     short* __restrict__ P) {
    __shared__ short As[2][128 * 64];   // [buf][row][4 i * 16 feats] XOR-swz
    __shared__ short Bs[2][256 * 64];   // [buf][o-pair row][2 o * 32 k] XOR-swz

    const int bid = blockIdx.x;
    const int xcd = bid & 7;
    const int kc  = xcd >> 1;                       // 2 XCDs share a 2MB B panel
    const int bm  = ((bid >> 3) << 1) | (xcd & 1);  // [0,64)
    const int n0 = bm * 128;
    const int i0 = kc * 128;
    const int kbase = i0 * 16;                      // k offset in Wb
    const int NKT = 64;                             // 128 i / 2 i-per-kt

    const int tid = threadIdx.x;
    const int wid = tid >> 6, lane = tid & 63;
    const int lrow = lane & 15, lk = lane >> 4;
    const int wr = wid >> 2, wc = wid & 3;          // 2 x 4 wave grid

    f32x4 acc[4][8];
#pragma unroll
    for (int a = 0; a < 4; ++a)
#pragma unroll
        for (int b = 0; b < 8; ++b) {
            f32x4 z = {0.f, 0.f, 0.f, 0.f};
            acc[a][b] = z;
        }

    // A staging: thread -> row nl, ONE x value (i = i0 + p*4 + isel), every 2 kt
    const int nl = tid >> 2, isel = tid & 3;
    const float* xrow = x + (n0 + nl) * 512 + i0 + isel;

    auto stageA = [&](short* Ab, float xx) {
        float s1, c1;
        __sincosf(xx, &s1, &c1);
        float c = c1, s = s1;
        i32x4 lo, hi;
#pragma unroll
        for (int g = 0; g < 8; ++g) {
            const int p = pkbf(c, s);
            if (g < 4) lo[g] = p; else hi[g - 4] = p;
            const float t1 = s * s1, t2 = c * s1;
            const float cn = __builtin_fmaf(c, c1, -t1);
            s = __builtin_fmaf(s, c1, t2);
            c = cn;
        }
        const int cb0 = isel * 2;
        *(i32x4*)&Ab[nl * 64 + ((cb0 ^ (nl & 7))) * 8]       = lo;
        *(i32x4*)&Ab[nl * 64 + (((cb0 + 1) ^ (nl & 7))) * 8] = hi;
    };

    // B staging: tile = [512 o][32 k] bf16 = 32KB = 2048 x 16B chunks.
    // LDS row l (128B) holds o-rows {2l, 2l+1}; logical chunk cb = (o&1)*4 + kchunk,
    // stored at physical slot cb ^ (l&7). gload_lds dest is linear; source is
    // inverse-swizzled (rule 21).
    auto stageB = [&](int t, int nb) {
#pragma unroll
        for (int w = 0; w < 4; ++w) {
            const int ch = w * 512 + tid;           // physical chunk index
            const int l = ch >> 3, sl = ch & 7;
            const int cb = sl ^ (l & 7);
            const int r = 2 * l + (cb >> 2);
            const short* src = Wb + (size_t)r * KDIM + kbase + t * 32 + (cb & 3) * 8;
            short* ldst = &Bs[nb][w * 4096 + wid * 512];  // wave-uniform base
            __builtin_amdgcn_global_load_lds(
                (const __attribute__((address_space(1))) void*)src,
                (__attribute__((address_space(3))) void*)ldst, 16, 0, 0);
        }
    };

    float xv = xrow[0];                 // p = 0
    stageA(As[0], xv);
    stageB(0, 0);
    xv = xrow[4];                       // p = 1
    __syncthreads();

    for (int kt = 0; kt < NKT; ++kt) {
        const int bcur = kt & 1;
        const int abuf = (kt >> 1) & 1;

        // ---- fragment reads (first, so MFMA can start earliest)
        s16x8 af[4], bfr[8];
#pragma unroll
        for (int mf = 0; mf < 4; ++mf) {
            const int row = wr * 64 + mf * 16 + lrow;
            af[mf] = *(const s16x8*)&As[abuf][row * 64 + (((kt & 1) * 4 + lk) ^ (row & 7)) * 8];
        }
#pragma unroll
        for (int nf = 0; nf < 8; ++nf) {
            const int r = wc * 128 + nf * 16 + lrow;
            const int l = r >> 1;
            const int sl = (((r & 1) * 4 + lk) ^ (l & 7));
            bfr[nf] = *(const s16x8*)&Bs[bcur][l * 64 + sl * 8];
        }

        // ---- stage next tiles (overlap with MFMA below)
        if (kt + 1 < NKT) stageB(kt + 1, bcur ^ 1);
        if ((kt & 1) == 0 && kt + 2 < NKT) {
            stageA(As[abuf ^ 1], xv);                    // p = kt/2 + 1
            if (kt + 4 < NKT) xv = xrow[((kt >> 1) + 2) * 4];
        }

        // ---- MFMA (32 per wave per kt)
        __builtin_amdgcn_s_setprio(1);
#pragma unroll
        for (int mf = 0; mf < 4; ++mf)
#pragma unroll
            for (int nf = 0; nf < 8; ++nf)
                acc[mf][nf] = __builtin_amdgcn_mfma_f32_16x16x32_bf16(
                    af[mf], bfr[nf], acc[mf][nf], 0, 0, 0);
        __builtin_amdgcn_s_setprio(0);

        __syncthreads();
    }

    // ---- epilogue: bf16 partial, D layout col = lane&15, row = (lane>>4)*4+j
    unsigned short* dst = (unsigned short*)P + (size_t)kc * (NROWS * ODIM);
#pragma unroll
    for (int nf = 0; nf < 8; ++nf) {
        const int oc = wc * 128 + nf * 16 + lrow;
#pragma unroll
        for (int mf = 0; mf < 4; ++mf) {
            const f32x4 v = acc[mf][nf];
            const int rbase = n0 + wr * 64 + mf * 16 + lk * 4;
#pragma unroll
            for (int j = 0; j < 4; ++j)
                dst[(size_t)(rbase + j) * 512 + oc] = (unsigned short)f2bf(v[j]);
        }
    }
}

// ---- combine: out = sum_{q<4} f32(Pq) + bias ----
__global__ __launch_bounds__(256) void fkan_combine4(const short* __restrict__ P,
                                                     const float* __restrict__ bias,
                                                     float* __restrict__ out) {
    const int total = NROWS * ODIM;
    const int stride = gridDim.x * 256 * 8;
    for (int e = (blockIdx.x * 256 + threadIdx.x) * 8; e < total; e += stride) {
        s16x8 a = *(const s16x8*)(P + e);
        s16x8 b = *(const s16x8*)(P + total + e);
        s16x8 c = *(const s16x8*)(P + 2 * total + e);
        s16x8 d = *(const s16x8*)(P + 3 * total + e);
        const int col = e & 511;
        float4 c0 = *(const float4*)(bias + col);
        float4 c1 = *(const float4*)(bias + col + 4);
        float4 r0, r1;
        r0.x = (bf2f(a[0]) + bf2f(b[0])) + (bf2f(c[0]) + bf2f(d[0])) + c0.x;
        r0.y = (bf2f(a[1]) + bf2f(b[1])) + (bf2f(c[1]) + bf2f(d[1])) + c0.y;
        r0.z = (bf2f(a[2]) + bf2f(b[2])) + (bf2f(c[2]) + bf2f(d[2])) + c0.z;
        r0.w = (bf2f(a[3]) + bf2f(b[3])) + (bf2f(c[3]) + bf2f(d[3])) + c0.w;
        r1.x = (bf2f(a[4]) + bf2f(b[4])) + (bf2f(c[4]) + bf2f(d[4])) + c1.x;
        r1.y = (bf2f(a[5]) + bf2f(b[5])) + (bf2f(c[5]) + bf2f(d[5])) + c1.y;
        r1.z = (bf2f(a[6]) + bf2f(b[6])) + (bf2f(c[6]) + bf2f(d[6])) + c1.z;
        r1.w = (bf2f(a[7]) + bf2f(b[7])) + (bf2f(c[7]) + bf2f(d[7])) + c1.w;
        *(float4*)(out + e)     = r0;
        *(float4*)(out + e + 4) = r1;
    }
}

// ---- fallback (small ws): R6 KSPLIT=1 structure, grid 256, f32 out + bias ----
__global__ __launch_bounds__(256, 2) void fkan_gemm_fb(const float* __restrict__ x,
                                                       const short* __restrict__ Wb,
                                                       const float* __restrict__ bias,
                                                       float* __restrict__ outp) {
    __shared__ short As[2][128 * 64];
    __shared__ short Bs[2][128 * 64];
    const int bid = blockIdx.x;
    const int xcd = bid & 7, idx = bid >> 3;
    const int bn = xcd & 3, bm = idx + (xcd >> 2) * 32;
    const int n0 = bm * 128, o0 = bn * 128;
    const int tid = threadIdx.x;
    const int wid = tid >> 6, lane = tid & 63;
    const int lrow = lane & 15, lk = lane >> 4;
    const int wr = wid >> 1, wc = wid & 1;
    f32x4 acc[4][4];
#pragma unroll
    for (int a = 0; a < 4; ++a)
#pragma unroll
        for (int b = 0; b < 4; ++b) { f32x4 z = {0,0,0,0}; acc[a][b] = z; }
    const int nl = tid >> 1, isel = tid & 1;
    const float* xrow = x + (n0 + nl) * 512 + isel * 2;
    auto stage = [&](int t, int nb, float2 xvv) {
#pragma unroll
        for (int w = 0; w < 4; ++w) {
            const int chunk = w * 256 + tid;
            const int r = chunk >> 3, pc = chunk & 7;
            const int lc = pc ^ (r & 7);
            const short* src = Wb + (o0 + r) * KDIM + t * 64 + lc * 8;
            short* ldst = &Bs[nb][w * 2048 + wid * 512];
            __builtin_amdgcn_global_load_lds(
                (const __attribute__((address_space(1))) void*)src,
                (__attribute__((address_space(3))) void*)ldst, 16, 0, 0);
        }
#pragma unroll
        for (int ii = 0; ii < 2; ++ii) {
            const float xx = ii ? xvv.y : xvv.x;
            float s1, c1; __sincosf(xx, &s1, &c1);
            float c = c1, s = s1;
            i32x4 lo, hi;
#pragma unroll
            for (int g = 0; g < 8; ++g) {
                const int p = pkbf(c, s);
                if (g < 4) lo[g] = p; else hi[g - 4] = p;
                const float t1 = s * s1, t2 = c * s1;
                const float cn = __builtin_fmaf(c, c1, -t1);
                s = __builtin_fmaf(s, c1, t2); c = cn;
            }
            const int cb0 = (isel * 2 + ii) * 2;
            *(i32x4*)&As[nb][nl * 64 + ((cb0 ^ (nl & 7))) * 8]       = lo;
            *(i32x4*)&As[nb][nl * 64 + (((cb0 + 1) ^ (nl & 7))) * 8] = hi;
        }
    };
    float2 xv = *(const float2*)xrow;
    stage(0, 0, xv);
    xv = *(const float2*)(xrow + 4);
    __syncthreads();
    for (int kt = 0; kt < 128; ++kt) {
        const int cur = kt & 1;
        s16x8 af[2][4], bfr[2][4];
#pragma unroll
        for (int ksub = 0; ksub < 2; ++ksub) {
#pragma unroll
            for (int mf = 0; mf < 4; ++mf) {
                const int row = wr * 64 + mf * 16 + lrow;
                af[ksub][mf] = *(const s16x8*)&As[cur][row * 64 + ((ksub * 4 + lk) ^ (row & 7)) * 8];
            }
#pragma unroll
            for (int nf = 0; nf < 4; ++nf) {
                const int row = wc * 64 + nf * 16 + lrow;
                bfr[ksub][nf] = *(const s16x8*)&Bs[cur][row * 64 + ((ksub * 4 + lk) ^ (row & 7)) * 8];
            }
        }
        if (kt + 1 < 128) {
            stage(kt + 1, cur ^ 1, xv);
            if (kt + 2 < 128) xv = *(const float2*)(xrow + (kt + 2) * 4);
        }
#pragma unroll
        for (int ksub = 0; ksub < 2; ++ksub)
#pragma unroll
            for (int mf = 0; mf < 4; ++mf)
#pragma unroll
                for (int nf = 0; nf < 4; ++nf)
                    acc[mf][nf] = __builtin_amdgcn_mfma_f32_16x16x32_bf16(
                        af[ksub][mf], bfr[ksub][nf], acc[mf][nf], 0, 0, 0);
        __syncthreads();
    }
#pragma unroll
    for (int nf = 0; nf < 4; ++nf) {
        const int oc = o0 + wc * 64 + nf * 16 + lrow;
        const float bv = bias[oc];
#pragma unroll
        for (int mf = 0; mf < 4; ++mf) {
            const f32x4 v = acc[mf][nf];
            const int rbase = n0 + wr * 64 + mf * 16 + lk * 4;
#pragma unroll
            for (int j = 0; j < 4; ++j)
                outp[(size_t)(rbase + j) * 512 + oc] = v[j] + bv;
        }
    }
}

extern "C" void kernel_launch(void* const* d_in, const int* in_sizes, int n_in,
                              void* d_out, int out_size, void* d_ws, size_t ws_size,
                              hipStream_t stream) {
    const float* x    = (const float*)d_in[0];
    const float* cf   = (const float*)d_in[1];
    const float* bias = (const float*)d_in[2];
    float* out = (float*)d_out;

    const size_t partial_bytes = (size_t)4 * NROWS * ODIM * 2;   // 33.6 MB (bf16 x4)
    const size_t wb_bytes = (size_t)ODIM * KDIM * 2;             // 8.4 MB

    if (ws_size >= partial_bytes + wb_bytes) {
        short* P  = (short*)d_ws;
        short* Wb = (short*)((char*)d_ws + partial_bytes);
        fkan_prep<<<512, 256, 0, stream>>>(cf, Wb);
        fkan_gemm4<<<256, 512, 0, stream>>>(x, Wb, P);
        fkan_combine4<<<2048, 256, 0, stream>>>(P, bias, out);
    } else {
        short* Wb = (short*)d_ws;
        fkan_prep<<<512, 256, 0, stream>>>(cf, Wb);
        fkan_gemm_fb<<<256, 256, 0, stream>>>(x, Wb, bias, out);
    }
}

// Round 8
// 91.747 us; speedup vs baseline: 1.6347x; 1.0089x over previous
//
#include <hip/hip_runtime.h>
#include <hip/hip_bf16.h>

// FourierKANLayer: y[n,o] = sum_{i,g} cos(x[n,i]*(g+1))*C[0,o,i,g]
//                         + sin(x[n,i]*(g+1))*C[1,o,i,g] + bias[o]
// N=8192, I=512, O=512, G=8  ->  GEMM [N x K]*[K x O], K = I*16 = 8192
// Round 8: T3+T4 pipeline. Same geometry as R7 (BM=128,BN=512,BK=32, 8 waves,
// KSPLIT=4, grid 256) but raw s_barrier + COUNTED vmcnt (never 0 in steady
// state): B(kt+2) global_load_lds stays in flight across both barriers with a
// full MFMA phase of cover. x-prefetch folded into the vmcnt schedule.

typedef __attribute__((ext_vector_type(8))) short s16x8;
typedef __attribute__((ext_vector_type(4))) int   i32x4;
typedef __attribute__((ext_vector_type(4))) float f32x4;

#define NROWS 8192
#define IDIM  512
#define ODIM  512
#define KDIM  8192   // IDIM*16

static __device__ __forceinline__ short f2bf(float f) {
    union { float f; unsigned u; } v; v.f = f;
    unsigned r = v.u + 0x7fffu + ((v.u >> 16) & 1u);  // RNE
    return (short)(r >> 16);
}

static __device__ __forceinline__ float bf2f(short h) {
    union { unsigned u; float f; } v;
    v.u = ((unsigned)(unsigned short)h) << 16;
    return v.f;
}

static __device__ __forceinline__ int pkbf(float c, float s) {
    union { __hip_bfloat162 h; int i; } u;
    u.h = __float22bfloat162_rn(make_float2(c, s));   // low = cos, high = sin
    return u.i;
}

// ---- prep: coeffs [2][O][I][G] f32  ->  Wb[O][K] bf16, k = i*16 + 2g + t ----
__global__ __launch_bounds__(256) void fkan_prep(const float* __restrict__ cf,
                                                 short* __restrict__ Wb) {
    const int o = blockIdx.x;
    const int tid = threadIdx.x;
#pragma unroll
    for (int rep = 0; rep < 2; ++rep) {
        const int i = tid + rep * 256;
        const float* c0 = cf + (o * 512 + i) * 8;            // t=0
        const float* c1 = cf + ((512 + o) * 512 + i) * 8;    // t=1
        float4 a0 = *(const float4*)c0;
        float4 a1 = *(const float4*)(c0 + 4);
        float4 b0 = *(const float4*)c1;
        float4 b1 = *(const float4*)(c1 + 4);
        s16x8 lo, hi;
        lo[0] = f2bf(a0.x); lo[1] = f2bf(b0.x);
        lo[2] = f2bf(a0.y); lo[3] = f2bf(b0.y);
        lo[4] = f2bf(a0.z); lo[5] = f2bf(b0.z);
        lo[6] = f2bf(a0.w); lo[7] = f2bf(b0.w);
        hi[0] = f2bf(a1.x); hi[1] = f2bf(b1.x);
        hi[2] = f2bf(a1.y); hi[3] = f2bf(b1.y);
        hi[4] = f2bf(a1.z); hi[5] = f2bf(b1.z);
        hi[6] = f2bf(a1.w); hi[7] = f2bf(b1.w);
        *(s16x8*)(Wb + o * KDIM + i * 16)     = lo;
        *(s16x8*)(Wb + o * KDIM + i * 16 + 8) = hi;
    }
}

// ---- main GEMM: BM=128, BN=512, BK=32, 512 threads (8 waves, 2x4) ----
// grid 256 (KSPLIT=4, 1 block/CU). Writes bf16 partial P[kc][N][O].
__global__ __launch_bounds__(512, 2) void fkan_gemm4(const float* __restrict__ x,
                                                     const short* __restrict__ Wb,
                                                     short* __restrict__ P) {
    __shared__ short As[2][128 * 64];   // [buf][row][4 i * 16 feats] XOR-swz
    __shared__ short Bs[2][256 * 64];   // [buf][o-pair row][2 o * 32 k] XOR-swz

    const int bid = blockIdx.x;
    const int xcd = bid & 7;
    const int kc  = xcd >> 1;                       // 2 XCDs share a 2MB B panel
    const int bm  = ((bid >> 3) << 1) | (xcd & 1);  // [0,64)
    const int n0 = bm * 128;
    const int i0 = kc * 128;
    const int kbase = i0 * 16;                      // k offset in Wb

    const int tid = threadIdx.x;
    const int wid = tid >> 6, lane = tid & 63;
    const int lrow = lane & 15, lk = lane >> 4;
    const int wr = wid >> 2, wc = wid & 3;          // 2 x 4 wave grid

    f32x4 acc[4][8];
#pragma unroll
    for (int a = 0; a < 4; ++a)
#pragma unroll
        for (int b = 0; b < 8; ++b) {
            f32x4 z = {0.f, 0.f, 0.f, 0.f};
            acc[a][b] = z;
        }

    // A staging: thread -> row nl, ONE x value (i = i0 + p*4 + isel) per p-block
    const int nl = tid >> 2, isel = tid & 3;
    const float* xrow = x + (n0 + nl) * 512 + i0 + isel;

    auto stageA = [&](short* Ab, float xx) {
        float s1, c1;
        __sincosf(xx, &s1, &c1);
        float c = c1, s = s1;
        i32x4 lo, hi;
#pragma unroll
        for (int g = 0; g < 8; ++g) {
            const int p = pkbf(c, s);
            if (g < 4) lo[g] = p; else hi[g - 4] = p;
            const float t1 = s * s1, t2 = c * s1;
            const float cn = __builtin_fmaf(c, c1, -t1);
            s = __builtin_fmaf(s, c1, t2);
            c = cn;
        }
        const int cb0 = isel * 2;
        *(i32x4*)&Ab[nl * 64 + ((cb0 ^ (nl & 7))) * 8]       = lo;
        *(i32x4*)&Ab[nl * 64 + (((cb0 + 1) ^ (nl & 7))) * 8] = hi;
    };

    // B staging: tile [512 o][32 k] = 32KB = 2048 x 16B chunks; LDS row l
    // (128B) holds o-rows {2l,2l+1}; chunk cb stored at slot cb ^ (l&7);
    // gload_lds dest linear, source inverse-swizzled (rule 21).
    auto stageB = [&](int t, int nb) {
#pragma unroll
        for (int w = 0; w < 4; ++w) {
            const int ch = w * 512 + tid;           // physical chunk index
            const int l = ch >> 3, sl = ch & 7;
            const int cb = sl ^ (l & 7);
            const int r = 2 * l + (cb >> 2);
            const short* src = Wb + (size_t)r * KDIM + kbase + t * 32 + (cb & 3) * 8;
            short* ldst = &Bs[nb][w * 4096 + wid * 512];  // wave-uniform base
            __builtin_amdgcn_global_load_lds(
                (const __attribute__((address_space(1))) void*)src,
                (__attribute__((address_space(3))) void*)ldst, 16, 0, 0);
        }
    };

    // ---- prologue: A(p=0) staged, B(0),B(1) issued, x(p=1) in flight
    float xv0 = xrow[0];                // p=0
    float xv  = xrow[4];                // p=1 (consumed iter 0)
    stageA(As[0], xv0);
    stageB(0, 0);
    stageB(1, 1);
    // outstanding (oldest first): [xv(1), B0(4), B1(4)] -> complete xv+B0
    asm volatile("s_waitcnt vmcnt(4) lgkmcnt(0)" ::: "memory");
    __builtin_amdgcn_sched_barrier(0);
    __builtin_amdgcn_s_barrier();

#pragma unroll 1
    for (int kt2 = 0; kt2 < 32; ++kt2) {
        const int kt = kt2 * 2;
        short* Acur = As[kt2 & 1];
        short* Anxt = As[(kt2 + 1) & 1];

        // ================= even kt: Bs[0], A-chunks lk =================
        {
            s16x8 af[4], bfr[8];
#pragma unroll
            for (int mf = 0; mf < 4; ++mf) {
                const int row = wr * 64 + mf * 16 + lrow;
                af[mf] = *(const s16x8*)&Acur[row * 64 + ((lk) ^ (row & 7)) * 8];
            }
#pragma unroll
            for (int nf = 0; nf < 8; ++nf) {
                const int r = wc * 128 + nf * 16 + lrow;
                const int l = r >> 1;
                bfr[nf] = *(const s16x8*)&Bs[0][l * 64 + (((r & 1) * 4 + lk) ^ (l & 7)) * 8];
            }
            asm volatile("s_waitcnt lgkmcnt(0)" ::: "memory");   // reads landed
            __builtin_amdgcn_sched_barrier(0);
            __builtin_amdgcn_s_barrier();                        // #1

            if (kt2 < 31) {
                stageB(kt + 2, 0);          // overwrite Bs[0]; in flight 2 barriers
                stageA(Anxt, xv);           // p = kt2+1
                if (kt2 < 30) xv = xrow[(kt2 + 2) * 4];   // p = kt2+2
            }

            __builtin_amdgcn_s_setprio(1);
#pragma unroll
            for (int mf = 0; mf < 4; ++mf)
#pragma unroll
                for (int nf = 0; nf < 8; ++nf)
                    acc[mf][nf] = __builtin_amdgcn_mfma_f32_16x16x32_bf16(
                        af[mf], bfr[nf], acc[mf][nf], 0, 0, 0);
            __builtin_amdgcn_s_setprio(0);

            // need B(kt+1) done; leave B(kt+2)+x in flight
            if (kt2 < 30)
                asm volatile("s_waitcnt vmcnt(5) lgkmcnt(0)" ::: "memory");
            else if (kt2 == 30)
                asm volatile("s_waitcnt vmcnt(4) lgkmcnt(0)" ::: "memory");
            else
                asm volatile("s_waitcnt vmcnt(0) lgkmcnt(0)" ::: "memory");
            __builtin_amdgcn_sched_barrier(0);
            __builtin_amdgcn_s_barrier();                        // #2
        }

        // ================= odd kt: Bs[1], A-chunks 4+lk =================
        {
            s16x8 af[4], bfr[8];
#pragma unroll
            for (int mf = 0; mf < 4; ++mf) {
                const int row = wr * 64 + mf * 16 + lrow;
                af[mf] = *(const s16x8*)&Acur[row * 64 + ((4 + lk) ^ (row & 7)) * 8];
            }
#pragma unroll
            for (int nf = 0; nf < 8; ++nf) {
                const int r = wc * 128 + nf * 16 + lrow;
                const int l = r >> 1;
                bfr[nf] = *(const s16x8*)&Bs[1][l * 64 + (((r & 1) * 4 + lk) ^ (l & 7)) * 8];
            }
            asm volatile("s_waitcnt lgkmcnt(0)" ::: "memory");
            __builtin_amdgcn_sched_barrier(0);
            __builtin_amdgcn_s_barrier();                        // #1

            if (kt2 < 31) stageB(kt + 3, 1);

            __builtin_amdgcn_s_setprio(1);
#pragma unroll
            for (int mf = 0; mf < 4; ++mf)
#pragma unroll
                for (int nf = 0; nf < 8; ++nf)
                    acc[mf][nf] = __builtin_amdgcn_mfma_f32_16x16x32_bf16(
                        af[mf], bfr[nf], acc[mf][nf], 0, 0, 0);
            __builtin_amdgcn_s_setprio(0);

            // need B(kt+2) done (and x for next stageA); leave B(kt+3)
            if (kt2 < 30)
                asm volatile("s_waitcnt vmcnt(5)" ::: "memory");
            else if (kt2 == 30)
                asm volatile("s_waitcnt vmcnt(4)" ::: "memory");
            // kt2==31: nothing outstanding
            __builtin_amdgcn_sched_barrier(0);
            __builtin_amdgcn_s_barrier();                        // #2
        }
    }

    // ---- epilogue: bf16 partial, D layout col = lane&15, row = (lane>>4)*4+j
    unsigned short* dst = (unsigned short*)P + (size_t)kc * (NROWS * ODIM);
#pragma unroll
    for (int nf = 0; nf < 8; ++nf) {
        const int oc = wc * 128 + nf * 16 + lrow;
#pragma unroll
        for (int mf = 0; mf < 4; ++mf) {
            const f32x4 v = acc[mf][nf];
            const int rbase = n0 + wr * 64 + mf * 16 + lk * 4;
#pragma unroll
            for (int j = 0; j < 4; ++j)
                dst[(size_t)(rbase + j) * 512 + oc] = (unsigned short)f2bf(v[j]);
        }
    }
}

// ---- combine: out = sum_{q<4} f32(Pq) + bias ----
__global__ __launch_bounds__(256) void fkan_combine4(const short* __restrict__ P,
                                                     const float* __restrict__ bias,
                                                     float* __restrict__ out) {
    const int total = NROWS * ODIM;
    const int stride = gridDim.x * 256 * 8;
    for (int e = (blockIdx.x * 256 + threadIdx.x) * 8; e < total; e += stride) {
        s16x8 a = *(const s16x8*)(P + e);
        s16x8 b = *(const s16x8*)(P + total + e);
        s16x8 c = *(const s16x8*)(P + 2 * total + e);
        s16x8 d = *(const s16x8*)(P + 3 * total + e);
        const int col = e & 511;
        float4 c0 = *(const float4*)(bias + col);
        float4 c1 = *(const float4*)(bias + col + 4);
        float4 r0, r1;
        r0.x = (bf2f(a[0]) + bf2f(b[0])) + (bf2f(c[0]) + bf2f(d[0])) + c0.x;
        r0.y = (bf2f(a[1]) + bf2f(b[1])) + (bf2f(c[1]) + bf2f(d[1])) + c0.y;
        r0.z = (bf2f(a[2]) + bf2f(b[2])) + (bf2f(c[2]) + bf2f(d[2])) + c0.z;
        r0.w = (bf2f(a[3]) + bf2f(b[3])) + (bf2f(c[3]) + bf2f(d[3])) + c0.w;
        r1.x = (bf2f(a[4]) + bf2f(b[4])) + (bf2f(c[4]) + bf2f(d[4])) + c1.x;
        r1.y = (bf2f(a[5]) + bf2f(b[5])) + (bf2f(c[5]) + bf2f(d[5])) + c1.y;
        r1.z = (bf2f(a[6]) + bf2f(b[6])) + (bf2f(c[6]) + bf2f(d[6])) + c1.z;
        r1.w = (bf2f(a[7]) + bf2f(b[7])) + (bf2f(c[7]) + bf2f(d[7])) + c1.w;
        *(float4*)(out + e)     = r0;
        *(float4*)(out + e + 4) = r1;
    }
}

// ---- fallback (small ws): R6 KSPLIT=1 structure, grid 256, f32 out + bias ----
__global__ __launch_bounds__(256, 2) void fkan_gemm_fb(const float* __restrict__ x,
                                                       const short* __restrict__ Wb,
                                                       const float* __restrict__ bias,
                                                       float* __restrict__ outp) {
    __shared__ short As[2][128 * 64];
    __shared__ short Bs[2][128 * 64];
    const int bid = blockIdx.x;
    const int xcd = bid & 7, idx = bid >> 3;
    const int bn = xcd & 3, bm = idx + (xcd >> 2) * 32;
    const int n0 = bm * 128, o0 = bn * 128;
    const int tid = threadIdx.x;
    const int wid = tid >> 6, lane = tid & 63;
    const int lrow = lane & 15, lk = lane >> 4;
    const int wr = wid >> 1, wc = wid & 1;
    f32x4 acc[4][4];
#pragma unroll
    for (int a = 0; a < 4; ++a)
#pragma unroll
        for (int b = 0; b < 4; ++b) { f32x4 z = {0,0,0,0}; acc[a][b] = z; }
    const int nl = tid >> 1, isel = tid & 1;
    const float* xrow = x + (n0 + nl) * 512 + isel * 2;
    auto stage = [&](int t, int nb, float2 xvv) {
#pragma unroll
        for (int w = 0; w < 4; ++w) {
            const int chunk = w * 256 + tid;
            const int r = chunk >> 3, pc = chunk & 7;
            const int lc = pc ^ (r & 7);
            const short* src = Wb + (o0 + r) * KDIM + t * 64 + lc * 8;
            short* ldst = &Bs[nb][w * 2048 + wid * 512];
            __builtin_amdgcn_global_load_lds(
                (const __attribute__((address_space(1))) void*)src,
                (__attribute__((address_space(3))) void*)ldst, 16, 0, 0);
        }
#pragma unroll
        for (int ii = 0; ii < 2; ++ii) {
            const float xx = ii ? xvv.y : xvv.x;
            float s1, c1; __sincosf(xx, &s1, &c1);
            float c = c1, s = s1;
            i32x4 lo, hi;
#pragma unroll
            for (int g = 0; g < 8; ++g) {
                const int p = pkbf(c, s);
                if (g < 4) lo[g] = p; else hi[g - 4] = p;
                const float t1 = s * s1, t2 = c * s1;
                const float cn = __builtin_fmaf(c, c1, -t1);
                s = __builtin_fmaf(s, c1, t2); c = cn;
            }
            const int cb0 = (isel * 2 + ii) * 2;
            *(i32x4*)&As[nb][nl * 64 + ((cb0 ^ (nl & 7))) * 8]       = lo;
            *(i32x4*)&As[nb][nl * 64 + (((cb0 + 1) ^ (nl & 7))) * 8] = hi;
        }
    };
    float2 xv = *(const float2*)xrow;
    stage(0, 0, xv);
    xv = *(const float2*)(xrow + 4);
    __syncthreads();
    for (int kt = 0; kt < 128; ++kt) {
        const int cur = kt & 1;
        s16x8 af[2][4], bfr[2][4];
#pragma unroll
        for (int ksub = 0; ksub < 2; ++ksub) {
#pragma unroll
            for (int mf = 0; mf < 4; ++mf) {
                const int row = wr * 64 + mf * 16 + lrow;
                af[ksub][mf] = *(const s16x8*)&As[cur][row * 64 + ((ksub * 4 + lk) ^ (row & 7)) * 8];
            }
#pragma unroll
            for (int nf = 0; nf < 4; ++nf) {
                const int row = wc * 64 + nf * 16 + lrow;
                bfr[ksub][nf] = *(const s16x8*)&Bs[cur][row * 64 + ((ksub * 4 + lk) ^ (row & 7)) * 8];
            }
        }
        if (kt + 1 < 128) {
            stage(kt + 1, cur ^ 1, xv);
            if (kt + 2 < 128) xv = *(const float2*)(xrow + (kt + 2) * 4);
        }
#pragma unroll
        for (int ksub = 0; ksub < 2; ++ksub)
#pragma unroll
            for (int mf = 0; mf < 4; ++mf)
#pragma unroll
                for (int nf = 0; nf < 4; ++nf)
                    acc[mf][nf] = __builtin_amdgcn_mfma_f32_16x16x32_bf16(
                        af[ksub][mf], bfr[ksub][nf], acc[mf][nf], 0, 0, 0);
        __syncthreads();
    }
#pragma unroll
    for (int nf = 0; nf < 4; ++nf) {
        const int oc = o0 + wc * 64 + nf * 16 + lrow;
        const float bv = bias[oc];
#pragma unroll
        for (int mf = 0; mf < 4; ++mf) {
            const f32x4 v = acc[mf][nf];
            const int rbase = n0 + wr * 64 + mf * 16 + lk * 4;
#pragma unroll
            for (int j = 0; j < 4; ++j)
                outp[(size_t)(rbase + j) * 512 + oc] = v[j] + bv;
        }
    }
}

extern "C" void kernel_launch(void* const* d_in, const int* in_sizes, int n_in,
                              void* d_out, int out_size, void* d_ws, size_t ws_size,
                              hipStream_t stream) {
    const float* x    = (const float*)d_in[0];
    const float* cf   = (const float*)d_in[1];
    const float* bias = (const float*)d_in[2];
    float* out = (float*)d_out;

    const size_t partial_bytes = (size_t)4 * NROWS * ODIM * 2;   // 33.6 MB (bf16 x4)
    const size_t wb_bytes = (size_t)ODIM * KDIM * 2;             // 8.4 MB

    if (ws_size >= partial_bytes + wb_bytes) {
        short* P  = (short*)d_ws;
        short* Wb = (short*)((char*)d_ws + partial_bytes);
        fkan_prep<<<512, 256, 0, stream>>>(cf, Wb);
        fkan_gemm4<<<256, 512, 0, stream>>>(x, Wb, P);
        fkan_combine4<<<2048, 256, 0, stream>>>(P, bias, out);
    } else {
        short* Wb = (short*)d_ws;
        fkan_prep<<<512, 256, 0, stream>>>(cf, Wb);
        fkan_gemm_fb<<<256, 256, 0, stream>>>(x, Wb, bias, out);
    }
}